// Round 1
// 117.122 us; speedup vs baseline: 1.0453x; 1.0453x over previous
//
#include <hip/hip_runtime.h>
#include <cstdint>

// Attention B=4, S=4096, WORD=512, ED=64, fp32 io. R8.
// R8 changes vs R7:
//  - attn: Ksplit 8 -> 6 (uneven 11/11/11/11/10/10 tiles), grid 768 = exactly
//    3 resident blocks/CU -> no 4th-round dispatch tail; opp 16.8->12.6 MB.
//  - v_cvt_pk_bf16_f32 (1 op) replaces pkru (3 ops) for all bf16 packing.
//  - lp tree-sum (break 16-deep serial add chain); s_setprio around compute.
//  - qkv_proj: 32 rows/block (grid 512) -> weight L2 traffic 201->100 MB.

typedef __bf16 bf16x8 __attribute__((ext_vector_type(8)));
typedef float f32x4 __attribute__((ext_vector_type(4)));
typedef float f32x16 __attribute__((ext_vector_type(16)));
typedef int i32x2 __attribute__((ext_vector_type(2)));

#define SCALEQ 0.18033688011112042f  // log2(e)/sqrt(64)

// ws layout (bytes)
#define WT_OFF 0u          // bf16 Wt2 frag-major [12ntg][16kc][64lane][8]
#define Q_OFF  262144u     // bf16 Q [16384][64] (scaled)
#define KV_OFF 2359296u    // bf16 kv[256 tiles][8192]  (K chunks 0-7, V 8-15)
#define L_OFF  6553600u    // f32 l [6][16384]
#define OP_OFF 7077888u    // bf16 op [6][16384][64]

#if defined(__has_builtin)
#if __has_builtin(__builtin_amdgcn_permlane32_swap)
#define HAVE_PLSWAP 1
#endif
#if __has_builtin(__builtin_amdgcn_global_load_lds)
#define HAVE_GLL 1
#endif
#endif
#ifndef HAVE_PLSWAP
#define HAVE_PLSWAP 0
#endif
#ifndef HAVE_GLL
#define HAVE_GLL 0
#endif

__device__ __forceinline__ unsigned short bf16_1(float a) {
  unsigned ua = __builtin_bit_cast(unsigned, a);
  ua += 0x7FFFu + ((ua >> 16) & 1u);
  return (unsigned short)(ua >> 16);
}
// packed f32x2 -> bf16x2 (lo in low half), single HW op on gfx950
__device__ __forceinline__ unsigned cvtpk(float lo, float hi) {
  unsigned r;
  asm("v_cvt_pk_bf16_f32 %0, %1, %2" : "=v"(r) : "v"(lo), "v"(hi));
  return r;
}
__device__ __forceinline__ void plswap(unsigned& x, unsigned& y, unsigned hl) {
#if HAVE_PLSWAP
  i32x2 r = __builtin_amdgcn_permlane32_swap((int)x, (int)y, false, false);
  x = (unsigned)r[0];
  y = (unsigned)r[1];
#else
  unsigned xs = (unsigned)__shfl_xor((int)x, 32);
  unsigned ys = (unsigned)__shfl_xor((int)y, 32);
  unsigned nx = hl ? ys : x;
  unsigned ny = hl ? y : xs;
  x = nx;
  y = ny;
#endif
}
#if HAVE_GLL
__device__ __forceinline__ void gll16(const void* g, void* l) {
  __builtin_amdgcn_global_load_lds(
      (const __attribute__((address_space(1))) void*)g,
      (__attribute__((address_space(3))) void*)l, 16, 0, 0);
}
#endif

// ------------- kernel 0: W -> frag-major bf16 Wt2 --------------------------
__global__ __launch_bounds__(256) void prep_w(const float* __restrict__ Wq,
                                              const float* __restrict__ Wk,
                                              const float* __restrict__ Wv,
                                              unsigned short* __restrict__ wt2) {
  unsigned gtid = blockIdx.x * 256u + threadIdx.x;  // 98304
  unsigned mat = gtid >> 15, rem = gtid & 32767u;
  const float* w = (mat == 0) ? Wq : (mat == 1) ? Wk : Wv;
  float v = w[rem];  // coalesced [k][n]
  unsigned k = rem >> 6, n = rem & 63u;
  unsigned col = mat * 64u + n;
  unsigned ntg = col >> 4, l15c = col & 15u;
  unsigned kc = k >> 5, quad = (k >> 3) & 3u, j = k & 7u;
  wt2[((ntg * 16u + kc) * 64u + quad * 16u + l15c) * 8u + j] = bf16_1(v);
}

// ------------- kernel 1: QKV projection (32 rows/block, grid 512) ----------
__global__ __launch_bounds__(256, 4) void qkv_proj(
    const float* __restrict__ x, const unsigned short* __restrict__ wt2,
    const float* __restrict__ bq, const float* __restrict__ bk,
    const float* __restrict__ bv, unsigned short* __restrict__ qws,
    unsigned short* __restrict__ kvws) {
  __shared__ __align__(16) char xs[32768];  // 32 rows x 512k bf16 swizzled
  __shared__ float biasl[192];
  const unsigned t = threadIdx.x;
  const unsigned row0 = blockIdx.x * 32u;
  const unsigned w = t >> 6, lane = t & 63u, l15 = lane & 15u, quad = lane >> 4;

  if (t < 192u) {
    unsigned mat = t >> 6, n = t & 63u;
    biasl[t] = (mat == 0) ? bq[n] : (mat == 1) ? bk[n] : bv[n];
  }
#pragma unroll
  for (int i = 0; i < 16; i++) {  // stage x fp32 -> bf16, swizzled
    unsigned idx4 = t + 256u * (unsigned)i;
    unsigned fidx = idx4 * 4u;
    unsigned row = fidx >> 9, k = fidx & 511u, g = k >> 3;
    float4 f = *(const float4*)(x + row0 * 512u + fidx);
    int2 v = make_int2((int)cvtpk(f.x, f.y), (int)cvtpk(f.z, f.w));
    *(int2*)(xs + row * 1024u + ((g ^ (row & 7u)) << 4) + (k & 7u) * 2u) = v;
  }
  __syncthreads();

  f32x4 acc[2][3];
#pragma unroll
  for (int rg = 0; rg < 2; rg++)
#pragma unroll
    for (int i = 0; i < 3; i++) acc[rg][i] = {0.f, 0.f, 0.f, 0.f};
  const unsigned short* wbase = wt2 + (w * 3u * 1024u + lane) * 8u;

  int4 cur[3], nxt[3];
#pragma unroll
  for (int nt = 0; nt < 3; nt++)  // each frag load = 1KB fully contiguous
    cur[nt] = *(const int4*)(wbase + (unsigned)nt * 8192u);
  for (unsigned kc = 0; kc < 16u; kc++) {
    if (kc < 15u) {
#pragma unroll
      for (int nt = 0; nt < 3; nt++)
        nxt[nt] = *(const int4*)(wbase + ((unsigned)nt * 16u + kc + 1u) * 512u);
    }
    unsigned ag = kc * 4u + quad;
    unsigned r1 = 16u + l15;
    int4 av0 = *(const int4*)(xs + l15 * 1024u + ((ag ^ (l15 & 7u)) << 4));
    int4 av1 = *(const int4*)(xs + r1 * 1024u + ((ag ^ (r1 & 7u)) << 4));
    bf16x8 a0 = __builtin_bit_cast(bf16x8, av0);
    bf16x8 a1 = __builtin_bit_cast(bf16x8, av1);
#pragma unroll
    for (int nt = 0; nt < 3; nt++)
      acc[0][nt] = __builtin_amdgcn_mfma_f32_16x16x32_bf16(
          a0, __builtin_bit_cast(bf16x8, cur[nt]), acc[0][nt], 0, 0, 0);
#pragma unroll
    for (int nt = 0; nt < 3; nt++)
      acc[1][nt] = __builtin_amdgcn_mfma_f32_16x16x32_bf16(
          a1, __builtin_bit_cast(bf16x8, cur[nt]), acc[1][nt], 0, 0, 0);
#pragma unroll
    for (int nt = 0; nt < 3; nt++) cur[nt] = nxt[nt];
  }
#pragma unroll
  for (int rg = 0; rg < 2; rg++) {
    unsigned sb = row0 + (unsigned)rg * 16u + quad * 4u;
#pragma unroll
    for (int nt = 0; nt < 3; nt++) {
      unsigned col = w * 48u + (unsigned)nt * 16u + l15;
      unsigned mat = col >> 6, n = col & 63u;
      float bb = biasl[col];
      if (mat == 0) {
#pragma unroll
        for (int r = 0; r < 4; r++)
          qws[(sb + (unsigned)r) * 64u + n] =
              bf16_1((acc[rg][nt][r] + bb) * SCALEQ);
      } else if (mat == 1) {
        // K frag-major: kv[tile][n>>3][kappa][n&7], chunks 0..7
#pragma unroll
        for (int r = 0; r < 4; r++) {
          unsigned s = sb + (unsigned)r;
          unsigned bb2 = s >> 12, tile = (s & 4095u) >> 6, kap = s & 63u;
          kvws[(bb2 * 64u + tile) * 8192u + (n >> 3) * 512u + kap * 8u +
               (n & 7u)] = bf16_1(acc[rg][nt][r] + bb);
        }
      } else {
        // V frag-major: kv[tile][8 + kg][d=n][kappa&7], chunks 8..15
        unsigned s = sb;
        unsigned bb2 = s >> 12, tile = (s & 4095u) >> 6;
        unsigned kg = (s & 63u) >> 3, j0 = s & 7u;
        int2 pv =
            make_int2((int)cvtpk(acc[rg][nt][0] + bb, acc[rg][nt][1] + bb),
                      (int)cvtpk(acc[rg][nt][2] + bb, acc[rg][nt][3] + bb));
        *(int2*)(kvws + (bb2 * 64u + tile) * 8192u + (8u + kg) * 512u + n * 8u +
                 j0) = pv;
      }
    }
  }
}

// ------------- kernel 2: flash attention (Ksplit 6, grid 768) --------------
// Grid 768 = exactly 3 resident blocks/CU (launch_bounds 256,3): every block
// resident from t=0, no redispatch tail. Split ks covers 11 tiles (ks<4) or
// 10 tiles (ks>=4). Per iter: ds_read all frags -> regs, issue DMA prefetch,
// compute from regs only (setprio 1), one barrier.
__global__ __launch_bounds__(256, 3) void attn(
    const unsigned short* __restrict__ qws,
    const unsigned short* __restrict__ kvws, float* __restrict__ lws,
    unsigned short* __restrict__ opp) {
  __shared__ __align__(16) char sm[34816];  // dbuf 2x16KB; epilogue 4x8704
  const unsigned t = threadIdx.x;
  const unsigned w = t >> 6, lane = t & 63u, l31 = lane & 31u, hl = lane >> 5;
  const unsigned bid = blockIdx.x;
  const unsigned ks = bid >> 7;            // 0..5
  const unsigned b = (bid >> 5) & 3u;
  const unsigned qt = bid & 31u;
  const unsigned q0 = qt * 128u + w * 32u;
  const unsigned tile0 = ks * 10u + (ks < 4u ? ks : 4u);  // 0,11,22,33,44,54
  const unsigned ntl = (ks < 4u) ? 11u : 10u;
  const unsigned short* kvb = kvws + (b * 64u + tile0) * 8192u + lane * 8u;

  bf16x8 qf[4];
#pragma unroll
  for (int kq = 0; kq < 4; kq++)
    qf[kq] = __builtin_bit_cast(
        bf16x8, *(const int4*)(qws + (b * 4096u + q0 + l31) * 64u +
                               (unsigned)kq * 16u + hl * 8u));
  f32x16 accO[2];
#pragma unroll
  for (int dh = 0; dh < 2; dh++)
#pragma unroll
    for (int r = 0; r < 16; r++) accO[dh][r] = 0.f;
  float lsum = 0.f;

#if HAVE_GLL
#define STAGE(kt_, bi_)                                                \
  {                                                                    \
    _Pragma("unroll") for (int i = 0; i < 4; i++) {                    \
      unsigned c = (unsigned)i * 4u + w;                               \
      gll16(kvb + (kt_)*8192u + c * 512u, sm + (bi_)*16384u + c * 1024u); \
    }                                                                  \
  }
  STAGE(0u, 0u);
  __syncthreads();
#else
  int4 stg[4];
#define LOADT(kt_)                                                         \
  {                                                                        \
    _Pragma("unroll") for (int i = 0; i < 4; i++) stg[i] =                 \
        *(const int4*)(kvb + (kt_)*8192u + ((unsigned)i * 4u + w) * 512u); \
  }
  LOADT(0u);
  {
#pragma unroll
    for (int i = 0; i < 4; i++)
      *(int4*)(sm + ((unsigned)i * 4u + w) * 1024u + lane * 16u) = stg[i];
  }
  __syncthreads();
#endif

  for (unsigned kt = 0; kt < ntl; kt++) {
    char* kb = sm + (kt & 1u) * 16384u;
    // (1) all frag reads -> registers (before any new LDS-DMA issue)
    int4 kfr[8], vfr[8];
#pragma unroll
    for (int kq = 0; kq < 4; kq++)
#pragma unroll
      for (int kh = 0; kh < 2; kh++)
        kfr[kq * 2 + kh] = *(const int4*)(
            kb + (((unsigned)kq * 2u + hl) * 64u + (unsigned)kh * 32u + l31) * 16u);
#pragma unroll
    for (int kqg = 0; kqg < 4; kqg++)
#pragma unroll
      for (int dh = 0; dh < 2; dh++)
        vfr[kqg * 2 + dh] = *(const int4*)(
            kb + 8192u +
            (((unsigned)kqg * 2u + hl) * 64u + (unsigned)dh * 32u + l31) * 16u);
    // (2) prefetch next tile
#if HAVE_GLL
    if (kt + 1u < ntl) STAGE(kt + 1u, (kt + 1u) & 1u);
#else
    if (kt + 1u < ntl) LOADT(kt + 1u);
#endif
    // (3) compute entirely from registers
    __builtin_amdgcn_s_setprio(1);
#pragma unroll
    for (int kh = 0; kh < 2; kh++) {
      f32x16 z;
#pragma unroll
      for (int r = 0; r < 16; r++) z[r] = 0.f;
#pragma unroll
      for (int kq = 0; kq < 4; kq++)
        z = __builtin_amdgcn_mfma_f32_32x32x16_bf16(
            __builtin_bit_cast(bf16x8, kfr[kq * 2 + kh]), qf[kq], z, 0, 0, 0);
#pragma unroll
      for (int r = 0; r < 16; r++) z[r] = __builtin_amdgcn_exp2f(z[r]);
      // tree-sum (break the serial dependent-add chain)
      float s0 = (z[0] + z[1]) + (z[2] + z[3]);
      float s1 = (z[4] + z[5]) + (z[6] + z[7]);
      float s2 = (z[8] + z[9]) + (z[10] + z[11]);
      float s3 = (z[12] + z[13]) + (z[14] + z[15]);
      lsum += (s0 + s1) + (s2 + s3);
      unsigned pk8[8];
#pragma unroll
      for (int c2 = 0; c2 < 4; c2++) {
        pk8[2 * c2] = cvtpk(z[4 * c2 + 0], z[4 * c2 + 1]);
        pk8[2 * c2 + 1] = cvtpk(z[4 * c2 + 2], z[4 * c2 + 3]);
      }
#pragma unroll
      for (int kqpl = 0; kqpl < 2; kqpl++) {
        unsigned a0 = pk8[4 * kqpl + 0], a1 = pk8[4 * kqpl + 1];
        unsigned b0 = pk8[4 * kqpl + 2], b1 = pk8[4 * kqpl + 3];
        plswap(a0, b0, hl);
        plswap(a1, b1, hl);
        int4 fr = make_int4((int)a0, (int)a1, (int)b0, (int)b1);
        bf16x8 pf = __builtin_bit_cast(bf16x8, fr);
        unsigned kqg = (unsigned)kh * 2u + (unsigned)kqpl;
#pragma unroll
        for (int dh = 0; dh < 2; dh++)
          accO[dh] = __builtin_amdgcn_mfma_f32_32x32x16_bf16(
              __builtin_bit_cast(bf16x8, vfr[kqg * 2u + (unsigned)dh]), pf,
              accO[dh], 0, 0, 0);
      }
    }
    __builtin_amdgcn_s_setprio(0);
    // (4) barrier (drains DMA; overlapped by the compute above)
    __syncthreads();
#if !HAVE_GLL
    if (kt + 1u < ntl) {
#pragma unroll
      for (int i = 0; i < 4; i++)
        *(int4*)(sm + ((kt + 1u) & 1u) * 16384u +
                 ((unsigned)i * 4u + w) * 1024u + lane * 16u) = stg[i];
      __syncthreads();
    }
#endif
  }
  // epilogue: l + bf16 O-partials via wave-private LDS transpose
  float lt = lsum + __shfl_xor(lsum, 32);
  if (hl == 0u) lws[ks * 16384u + b * 4096u + q0 + l31] = lt;
  float* sc = (float*)(sm + w * 8704u);  // 32q x 68 floats
#pragma unroll
  for (int dh = 0; dh < 2; dh++)
#pragma unroll
    for (int r = 0; r < 16; r++) {
      unsigned d = (unsigned)dh * 32u + (unsigned)(r & 3) +
                   8u * (unsigned)(r >> 2) + 4u * hl;
      sc[l31 * 68u + d] = accO[dh][r];
    }
#pragma unroll
  for (int i = 0; i < 4; i++) {
    unsigned ql = (lane >> 3) + (unsigned)i * 8u;
    unsigned d0 = (lane & 7u) * 8u;
    float4 f0 = *(const float4*)(sc + ql * 68u + d0);
    float4 f1 = *(const float4*)(sc + ql * 68u + d0 + 4u);
    int4 pv = make_int4((int)cvtpk(f0.x, f0.y), (int)cvtpk(f0.z, f0.w),
                        (int)cvtpk(f1.x, f1.y), (int)cvtpk(f1.z, f1.w));
    *(int4*)(opp + ks * 1048576u + (b * 4096u + q0 + ql) * 64u + d0) = pv;
  }
}

// ------------- kernel 3: combine 6 partials + normalize (grid 512) ---------
__global__ __launch_bounds__(256) void combine(const unsigned short* __restrict__ opp,
                                               const float* __restrict__ lws,
                                               float* __restrict__ out) {
#pragma unroll
  for (int ii = 0; ii < 2; ii++) {
    unsigned slot = blockIdx.x * 512u + threadIdx.x + 256u * (unsigned)ii;
    unsigned q = slot >> 4, c = (slot & 15u) * 4u;
    float l = 0.f;
#pragma unroll
    for (int s = 0; s < 6; s++) l += lws[(unsigned)s * 16384u + q];
    float inv = 1.0f / l;
    float4 r = make_float4(0.f, 0.f, 0.f, 0.f);
#pragma unroll
    for (int s = 0; s < 6; s++) {
      int2 pv = *(const int2*)(opp + (unsigned)s * 1048576u + q * 64u + c);
      r.x += __builtin_bit_cast(float, (unsigned)pv.x << 16);
      r.y += __builtin_bit_cast(float, (unsigned)pv.x & 0xFFFF0000u);
      r.z += __builtin_bit_cast(float, (unsigned)pv.y << 16);
      r.w += __builtin_bit_cast(float, (unsigned)pv.y & 0xFFFF0000u);
    }
    r.x *= inv; r.y *= inv; r.z *= inv; r.w *= inv;
    *(float4*)(out + q * 64u + c) = r;
  }
}

extern "C" void kernel_launch(void* const* d_in, const int* in_sizes, int n_in,
                              void* d_out, int out_size, void* d_ws,
                              size_t ws_size, hipStream_t stream) {
  const float* x = (const float*)d_in[0];
  const float* Wq = (const float*)d_in[1];
  const float* bq = (const float*)d_in[2];
  const float* Wk = (const float*)d_in[3];
  const float* bk = (const float*)d_in[4];
  const float* Wv = (const float*)d_in[5];
  const float* bv = (const float*)d_in[6];
  char* ws = (char*)d_ws;
  unsigned short* wt2 = (unsigned short*)(ws + WT_OFF);
  unsigned short* qb = (unsigned short*)(ws + Q_OFF);
  unsigned short* kvb = (unsigned short*)(ws + KV_OFF);
  float* lp = (float*)(ws + L_OFF);
  unsigned short* opp = (unsigned short*)(ws + OP_OFF);
  float* outp = (float*)d_out;

  prep_w<<<384, 256, 0, stream>>>(Wq, Wk, Wv, wt2);
  qkv_proj<<<512, 256, 0, stream>>>(x, wt2, bq, bk, bv, qb, kvb);
  attn<<<768, 256, 0, stream>>>(qb, kvb, lp, opp);
  combine<<<512, 256, 0, stream>>>(opp, lp, outp);
}

// Round 2
// 114.737 us; speedup vs baseline: 1.0670x; 1.0208x over previous
//
#include <hip/hip_runtime.h>
#include <cstdint>

// Attention B=4, S=4096, WORD=512, ED=64, fp32 io. R9.
// R9 vs R8: attn waves process TWO 32-row q-tiles (64 q/wave, 256 q/block).
// Same K/V ds_reads now feed 2x MFMA work -> LDS-read traffic per FLOP
// halves (was the bottleneck: 64KB ds_read per 16KB staged tile), KV L2
// traffic halves. Grid 64 qb x Ksplit 8 = 512 = exactly 2 blocks/CU
// (launch_bounds(256,2), ~220 VGPR). Combine back to 8 splits.

typedef __bf16 bf16x8 __attribute__((ext_vector_type(8)));
typedef float f32x4 __attribute__((ext_vector_type(4)));
typedef float f32x16 __attribute__((ext_vector_type(16)));
typedef int i32x2 __attribute__((ext_vector_type(2)));

#define SCALEQ 0.18033688011112042f  // log2(e)/sqrt(64)

// ws layout (bytes)
#define WT_OFF 0u          // bf16 Wt2 frag-major [12ntg][16kc][64lane][8]
#define Q_OFF  262144u     // bf16 Q [16384][64] (scaled)
#define KV_OFF 2359296u    // bf16 kv[256 tiles][8192]  (K chunks 0-7, V 8-15)
#define L_OFF  6553600u    // f32 l [8][16384]
#define OP_OFF 7077888u    // bf16 op [8][16384][64]

#if defined(__has_builtin)
#if __has_builtin(__builtin_amdgcn_permlane32_swap)
#define HAVE_PLSWAP 1
#endif
#if __has_builtin(__builtin_amdgcn_global_load_lds)
#define HAVE_GLL 1
#endif
#endif
#ifndef HAVE_PLSWAP
#define HAVE_PLSWAP 0
#endif
#ifndef HAVE_GLL
#define HAVE_GLL 0
#endif

__device__ __forceinline__ unsigned short bf16_1(float a) {
  unsigned ua = __builtin_bit_cast(unsigned, a);
  ua += 0x7FFFu + ((ua >> 16) & 1u);
  return (unsigned short)(ua >> 16);
}
// packed f32x2 -> bf16x2 (lo in low half), single HW op on gfx950
__device__ __forceinline__ unsigned cvtpk(float lo, float hi) {
  unsigned r;
  asm("v_cvt_pk_bf16_f32 %0, %1, %2" : "=v"(r) : "v"(lo), "v"(hi));
  return r;
}
__device__ __forceinline__ void plswap(unsigned& x, unsigned& y, unsigned hl) {
#if HAVE_PLSWAP
  i32x2 r = __builtin_amdgcn_permlane32_swap((int)x, (int)y, false, false);
  x = (unsigned)r[0];
  y = (unsigned)r[1];
#else
  unsigned xs = (unsigned)__shfl_xor((int)x, 32);
  unsigned ys = (unsigned)__shfl_xor((int)y, 32);
  unsigned nx = hl ? ys : x;
  unsigned ny = hl ? y : xs;
  x = nx;
  y = ny;
#endif
}
#if HAVE_GLL
__device__ __forceinline__ void gll16(const void* g, void* l) {
  __builtin_amdgcn_global_load_lds(
      (const __attribute__((address_space(1))) void*)g,
      (__attribute__((address_space(3))) void*)l, 16, 0, 0);
}
#endif

// ------------- kernel 0: W -> frag-major bf16 Wt2 --------------------------
__global__ __launch_bounds__(256) void prep_w(const float* __restrict__ Wq,
                                              const float* __restrict__ Wk,
                                              const float* __restrict__ Wv,
                                              unsigned short* __restrict__ wt2) {
  unsigned gtid = blockIdx.x * 256u + threadIdx.x;  // 98304
  unsigned mat = gtid >> 15, rem = gtid & 32767u;
  const float* w = (mat == 0) ? Wq : (mat == 1) ? Wk : Wv;
  float v = w[rem];  // coalesced [k][n]
  unsigned k = rem >> 6, n = rem & 63u;
  unsigned col = mat * 64u + n;
  unsigned ntg = col >> 4, l15c = col & 15u;
  unsigned kc = k >> 5, quad = (k >> 3) & 3u, j = k & 7u;
  wt2[((ntg * 16u + kc) * 64u + quad * 16u + l15c) * 8u + j] = bf16_1(v);
}

// ------------- kernel 1: QKV projection (32 rows/block, grid 512) ----------
__global__ __launch_bounds__(256, 4) void qkv_proj(
    const float* __restrict__ x, const unsigned short* __restrict__ wt2,
    const float* __restrict__ bq, const float* __restrict__ bk,
    const float* __restrict__ bv, unsigned short* __restrict__ qws,
    unsigned short* __restrict__ kvws) {
  __shared__ __align__(16) char xs[32768];  // 32 rows x 512k bf16 swizzled
  __shared__ float biasl[192];
  const unsigned t = threadIdx.x;
  const unsigned row0 = blockIdx.x * 32u;
  const unsigned w = t >> 6, lane = t & 63u, l15 = lane & 15u, quad = lane >> 4;

  if (t < 192u) {
    unsigned mat = t >> 6, n = t & 63u;
    biasl[t] = (mat == 0) ? bq[n] : (mat == 1) ? bk[n] : bv[n];
  }
#pragma unroll
  for (int i = 0; i < 16; i++) {  // stage x fp32 -> bf16, swizzled
    unsigned idx4 = t + 256u * (unsigned)i;
    unsigned fidx = idx4 * 4u;
    unsigned row = fidx >> 9, k = fidx & 511u, g = k >> 3;
    float4 f = *(const float4*)(x + row0 * 512u + fidx);
    int2 v = make_int2((int)cvtpk(f.x, f.y), (int)cvtpk(f.z, f.w));
    *(int2*)(xs + row * 1024u + ((g ^ (row & 7u)) << 4) + (k & 7u) * 2u) = v;
  }
  __syncthreads();

  f32x4 acc[2][3];
#pragma unroll
  for (int rg = 0; rg < 2; rg++)
#pragma unroll
    for (int i = 0; i < 3; i++) acc[rg][i] = {0.f, 0.f, 0.f, 0.f};
  const unsigned short* wbase = wt2 + (w * 3u * 1024u + lane) * 8u;

  int4 cur[3], nxt[3];
#pragma unroll
  for (int nt = 0; nt < 3; nt++)  // each frag load = 1KB fully contiguous
    cur[nt] = *(const int4*)(wbase + (unsigned)nt * 8192u);
  for (unsigned kc = 0; kc < 16u; kc++) {
    if (kc < 15u) {
#pragma unroll
      for (int nt = 0; nt < 3; nt++)
        nxt[nt] = *(const int4*)(wbase + ((unsigned)nt * 16u + kc + 1u) * 512u);
    }
    unsigned ag = kc * 4u + quad;
    unsigned r1 = 16u + l15;
    int4 av0 = *(const int4*)(xs + l15 * 1024u + ((ag ^ (l15 & 7u)) << 4));
    int4 av1 = *(const int4*)(xs + r1 * 1024u + ((ag ^ (r1 & 7u)) << 4));
    bf16x8 a0 = __builtin_bit_cast(bf16x8, av0);
    bf16x8 a1 = __builtin_bit_cast(bf16x8, av1);
#pragma unroll
    for (int nt = 0; nt < 3; nt++)
      acc[0][nt] = __builtin_amdgcn_mfma_f32_16x16x32_bf16(
          a0, __builtin_bit_cast(bf16x8, cur[nt]), acc[0][nt], 0, 0, 0);
#pragma unroll
    for (int nt = 0; nt < 3; nt++)
      acc[1][nt] = __builtin_amdgcn_mfma_f32_16x16x32_bf16(
          a1, __builtin_bit_cast(bf16x8, cur[nt]), acc[1][nt], 0, 0, 0);
#pragma unroll
    for (int nt = 0; nt < 3; nt++) cur[nt] = nxt[nt];
  }
#pragma unroll
  for (int rg = 0; rg < 2; rg++) {
    unsigned sb = row0 + (unsigned)rg * 16u + quad * 4u;
#pragma unroll
    for (int nt = 0; nt < 3; nt++) {
      unsigned col = w * 48u + (unsigned)nt * 16u + l15;
      unsigned mat = col >> 6, n = col & 63u;
      float bb = biasl[col];
      if (mat == 0) {
#pragma unroll
        for (int r = 0; r < 4; r++)
          qws[(sb + (unsigned)r) * 64u + n] =
              bf16_1((acc[rg][nt][r] + bb) * SCALEQ);
      } else if (mat == 1) {
        // K frag-major: kv[tile][n>>3][kappa][n&7], chunks 0..7
#pragma unroll
        for (int r = 0; r < 4; r++) {
          unsigned s = sb + (unsigned)r;
          unsigned bb2 = s >> 12, tile = (s & 4095u) >> 6, kap = s & 63u;
          kvws[(bb2 * 64u + tile) * 8192u + (n >> 3) * 512u + kap * 8u +
               (n & 7u)] = bf16_1(acc[rg][nt][r] + bb);
        }
      } else {
        // V frag-major: kv[tile][8 + kg][d=n][kappa&7], chunks 8..15
        unsigned s = sb;
        unsigned bb2 = s >> 12, tile = (s & 4095u) >> 6;
        unsigned kg = (s & 63u) >> 3, j0 = s & 7u;
        int2 pv =
            make_int2((int)cvtpk(acc[rg][nt][0] + bb, acc[rg][nt][1] + bb),
                      (int)cvtpk(acc[rg][nt][2] + bb, acc[rg][nt][3] + bb));
        *(int2*)(kvws + (bb2 * 64u + tile) * 8192u + (8u + kg) * 512u + n * 8u +
                 j0) = pv;
      }
    }
  }
}

// ------------- kernel 2: flash attention (Ksplit 8, grid 512) --------------
// Each wave: TWO 32-row q-tiles (64 q). One block = 256 q rows. The 16
// ds_read_b128 of K/V per tile now feed 32 MFMAs (2x R8) -> LDS-read
// bytes/FLOP halved. 2 blocks/CU resident, balanced (512 = 2*256).
__global__ __launch_bounds__(256, 2) void attn(
    const unsigned short* __restrict__ qws,
    const unsigned short* __restrict__ kvws, float* __restrict__ lws,
    unsigned short* __restrict__ opp) {
  __shared__ __align__(16) char sm[34816];  // dbuf 2x16KB; epilogue 4x8704
  const unsigned t = threadIdx.x;
  const unsigned w = t >> 6, lane = t & 63u, l31 = lane & 31u, hl = lane >> 5;
  const unsigned bid = blockIdx.x;
  const unsigned ks = bid >> 6;  // 0..7
  const unsigned qb = bid & 63u;
  const unsigned b = qb >> 4;
  const unsigned s0 = (qb & 15u) * 256u + w * 64u;  // wave's first q row in b
  const unsigned short* kvb = kvws + (b * 64u + ks * 8u) * 8192u + lane * 8u;

  bf16x8 qf[2][4];
#pragma unroll
  for (int qt2 = 0; qt2 < 2; qt2++)
#pragma unroll
    for (int kq = 0; kq < 4; kq++)
      qf[qt2][kq] = __builtin_bit_cast(
          bf16x8,
          *(const int4*)(qws + (b * 4096u + s0 + (unsigned)qt2 * 32u + l31) * 64u +
                         (unsigned)kq * 16u + hl * 8u));
  f32x16 accO[2][2];  // [qt][dh]
#pragma unroll
  for (int qt2 = 0; qt2 < 2; qt2++)
#pragma unroll
    for (int dh = 0; dh < 2; dh++)
#pragma unroll
      for (int r = 0; r < 16; r++) accO[qt2][dh][r] = 0.f;
  float lsumA = 0.f, lsumB = 0.f;

#if HAVE_GLL
#define STAGE(kt_, bi_)                                                \
  {                                                                    \
    _Pragma("unroll") for (int i = 0; i < 4; i++) {                    \
      unsigned c = (unsigned)i * 4u + w;                               \
      gll16(kvb + (kt_)*8192u + c * 512u, sm + (bi_)*16384u + c * 1024u); \
    }                                                                  \
  }
  STAGE(0u, 0u);
  __syncthreads();
#else
  int4 stg[4];
#define LOADT(kt_)                                                         \
  {                                                                        \
    _Pragma("unroll") for (int i = 0; i < 4; i++) stg[i] =                 \
        *(const int4*)(kvb + (kt_)*8192u + ((unsigned)i * 4u + w) * 512u); \
  }
  LOADT(0u);
  {
#pragma unroll
    for (int i = 0; i < 4; i++)
      *(int4*)(sm + ((unsigned)i * 4u + w) * 1024u + lane * 16u) = stg[i];
  }
  __syncthreads();
#endif

#pragma unroll 1
  for (unsigned kt = 0; kt < 8u; kt++) {
    char* kb = sm + (kt & 1u) * 16384u;
    // (1) all frag reads -> registers (before any new LDS-DMA issue)
    int4 kfr[8], vfr[8];
#pragma unroll
    for (int kq = 0; kq < 4; kq++)
#pragma unroll
      for (int kh = 0; kh < 2; kh++)
        kfr[kq * 2 + kh] = *(const int4*)(
            kb + (((unsigned)kq * 2u + hl) * 64u + (unsigned)kh * 32u + l31) * 16u);
#pragma unroll
    for (int kqg = 0; kqg < 4; kqg++)
#pragma unroll
      for (int dh = 0; dh < 2; dh++)
        vfr[kqg * 2 + dh] = *(const int4*)(
            kb + 8192u +
            (((unsigned)kqg * 2u + hl) * 64u + (unsigned)dh * 32u + l31) * 16u);
    // (2) prefetch next tile
#if HAVE_GLL
    if (kt < 7u) STAGE(kt + 1u, (kt + 1u) & 1u);
#else
    if (kt < 7u) LOADT(kt + 1u);
#endif
    // (3) compute entirely from registers
    __builtin_amdgcn_s_setprio(1);
#pragma unroll
    for (int kh = 0; kh < 2; kh++) {
      f32x16 zA, zB;
#pragma unroll
      for (int r = 0; r < 16; r++) zA[r] = 0.f;
#pragma unroll
      for (int r = 0; r < 16; r++) zB[r] = 0.f;
#pragma unroll
      for (int kq = 0; kq < 4; kq++)
        zA = __builtin_amdgcn_mfma_f32_32x32x16_bf16(
            __builtin_bit_cast(bf16x8, kfr[kq * 2 + kh]), qf[0][kq], zA, 0, 0, 0);
#pragma unroll
      for (int kq = 0; kq < 4; kq++)
        zB = __builtin_amdgcn_mfma_f32_32x32x16_bf16(
            __builtin_bit_cast(bf16x8, kfr[kq * 2 + kh]), qf[1][kq], zB, 0, 0, 0);
#pragma unroll
      for (int r = 0; r < 16; r++) zA[r] = __builtin_amdgcn_exp2f(zA[r]);
#pragma unroll
      for (int r = 0; r < 16; r++) zB[r] = __builtin_amdgcn_exp2f(zB[r]);
      {
        float s0a = (zA[0] + zA[1]) + (zA[2] + zA[3]);
        float s1a = (zA[4] + zA[5]) + (zA[6] + zA[7]);
        float s2a = (zA[8] + zA[9]) + (zA[10] + zA[11]);
        float s3a = (zA[12] + zA[13]) + (zA[14] + zA[15]);
        lsumA += (s0a + s1a) + (s2a + s3a);
        float s0b = (zB[0] + zB[1]) + (zB[2] + zB[3]);
        float s1b = (zB[4] + zB[5]) + (zB[6] + zB[7]);
        float s2b = (zB[8] + zB[9]) + (zB[10] + zB[11]);
        float s3b = (zB[12] + zB[13]) + (zB[14] + zB[15]);
        lsumB += (s0b + s1b) + (s2b + s3b);
      }
      unsigned pkA[8], pkB[8];
#pragma unroll
      for (int c2 = 0; c2 < 4; c2++) {
        pkA[2 * c2] = cvtpk(zA[4 * c2 + 0], zA[4 * c2 + 1]);
        pkA[2 * c2 + 1] = cvtpk(zA[4 * c2 + 2], zA[4 * c2 + 3]);
        pkB[2 * c2] = cvtpk(zB[4 * c2 + 0], zB[4 * c2 + 1]);
        pkB[2 * c2 + 1] = cvtpk(zB[4 * c2 + 2], zB[4 * c2 + 3]);
      }
#pragma unroll
      for (int kqpl = 0; kqpl < 2; kqpl++) {
        unsigned kqg = (unsigned)kh * 2u + (unsigned)kqpl;
        unsigned a0 = pkA[4 * kqpl + 0], a1 = pkA[4 * kqpl + 1];
        unsigned b0 = pkA[4 * kqpl + 2], b1 = pkA[4 * kqpl + 3];
        plswap(a0, b0, hl);
        plswap(a1, b1, hl);
        int4 frA = make_int4((int)a0, (int)a1, (int)b0, (int)b1);
        bf16x8 pfA = __builtin_bit_cast(bf16x8, frA);
#pragma unroll
        for (int dh = 0; dh < 2; dh++)
          accO[0][dh] = __builtin_amdgcn_mfma_f32_32x32x16_bf16(
              __builtin_bit_cast(bf16x8, vfr[kqg * 2u + (unsigned)dh]), pfA,
              accO[0][dh], 0, 0, 0);
        unsigned c0 = pkB[4 * kqpl + 0], c1 = pkB[4 * kqpl + 1];
        unsigned d0 = pkB[4 * kqpl + 2], d1 = pkB[4 * kqpl + 3];
        plswap(c0, d0, hl);
        plswap(c1, d1, hl);
        int4 frB = make_int4((int)c0, (int)c1, (int)d0, (int)d1);
        bf16x8 pfB = __builtin_bit_cast(bf16x8, frB);
#pragma unroll
        for (int dh = 0; dh < 2; dh++)
          accO[1][dh] = __builtin_amdgcn_mfma_f32_32x32x16_bf16(
              __builtin_bit_cast(bf16x8, vfr[kqg * 2u + (unsigned)dh]), pfB,
              accO[1][dh], 0, 0, 0);
      }
    }
    __builtin_amdgcn_s_setprio(0);
    // (4) barrier (drains DMA; overlapped by the compute above)
    __syncthreads();
#if !HAVE_GLL
    if (kt < 7u) {
#pragma unroll
      for (int i = 0; i < 4; i++)
        *(int4*)(sm + ((kt + 1u) & 1u) * 16384u +
                 ((unsigned)i * 4u + w) * 1024u + lane * 16u) = stg[i];
      __syncthreads();
    }
#endif
  }
  // epilogue: l + bf16 O-partials via wave-private LDS transpose (2 passes)
  float* sc = (float*)(sm + w * 8704u);  // 32q x 68 floats, wave-private
#pragma unroll
  for (int qt2 = 0; qt2 < 2; qt2++) {
    float ls = (qt2 == 0) ? lsumA : lsumB;
    float lt = ls + __shfl_xor(ls, 32);
    unsigned qrow = s0 + (unsigned)qt2 * 32u;
    if (hl == 0u) lws[ks * 16384u + b * 4096u + qrow + l31] = lt;
#pragma unroll
    for (int dh = 0; dh < 2; dh++)
#pragma unroll
      for (int r = 0; r < 16; r++) {
        unsigned d = (unsigned)dh * 32u + (unsigned)(r & 3) +
                     8u * (unsigned)(r >> 2) + 4u * hl;
        sc[l31 * 68u + d] = accO[qt2][dh][r];
      }
#pragma unroll
    for (int i = 0; i < 4; i++) {
      unsigned ql = (lane >> 3) + (unsigned)i * 8u;
      unsigned d0 = (lane & 7u) * 8u;
      float4 f0 = *(const float4*)(sc + ql * 68u + d0);
      float4 f1 = *(const float4*)(sc + ql * 68u + d0 + 4u);
      int4 pv = make_int4((int)cvtpk(f0.x, f0.y), (int)cvtpk(f0.z, f0.w),
                          (int)cvtpk(f1.x, f1.y), (int)cvtpk(f1.z, f1.w));
      *(int4*)(opp + ks * 1048576u + (b * 4096u + qrow + ql) * 64u + d0) = pv;
    }
  }
}

// ------------- kernel 3: combine 8 partials + normalize (grid 512) ---------
__global__ __launch_bounds__(256) void combine(const unsigned short* __restrict__ opp,
                                               const float* __restrict__ lws,
                                               float* __restrict__ out) {
#pragma unroll
  for (int ii = 0; ii < 2; ii++) {
    unsigned slot = blockIdx.x * 512u + threadIdx.x + 256u * (unsigned)ii;
    unsigned q = slot >> 4, c = (slot & 15u) * 4u;
    float l = 0.f;
#pragma unroll
    for (int s = 0; s < 8; s++) l += lws[(unsigned)s * 16384u + q];
    float inv = 1.0f / l;
    float4 r = make_float4(0.f, 0.f, 0.f, 0.f);
#pragma unroll
    for (int s = 0; s < 8; s++) {
      int2 pv = *(const int2*)(opp + (unsigned)s * 1048576u + q * 64u + c);
      r.x += __builtin_bit_cast(float, (unsigned)pv.x << 16);
      r.y += __builtin_bit_cast(float, (unsigned)pv.x & 0xFFFF0000u);
      r.z += __builtin_bit_cast(float, (unsigned)pv.y << 16);
      r.w += __builtin_bit_cast(float, (unsigned)pv.y & 0xFFFF0000u);
    }
    r.x *= inv; r.y *= inv; r.z *= inv; r.w *= inv;
    *(float4*)(out + q * 64u + c) = r;
  }
}

extern "C" void kernel_launch(void* const* d_in, const int* in_sizes, int n_in,
                              void* d_out, int out_size, void* d_ws,
                              size_t ws_size, hipStream_t stream) {
  const float* x = (const float*)d_in[0];
  const float* Wq = (const float*)d_in[1];
  const float* bq = (const float*)d_in[2];
  const float* Wk = (const float*)d_in[3];
  const float* bk = (const float*)d_in[4];
  const float* Wv = (const float*)d_in[5];
  const float* bv = (const float*)d_in[6];
  char* ws = (char*)d_ws;
  unsigned short* wt2 = (unsigned short*)(ws + WT_OFF);
  unsigned short* qb = (unsigned short*)(ws + Q_OFF);
  unsigned short* kvb = (unsigned short*)(ws + KV_OFF);
  float* lp = (float*)(ws + L_OFF);
  unsigned short* opp = (unsigned short*)(ws + OP_OFF);
  float* outp = (float*)d_out;

  prep_w<<<384, 256, 0, stream>>>(Wq, Wk, Wv, wt2);
  qkv_proj<<<512, 256, 0, stream>>>(x, wt2, bq, bk, bv, qb, kvb);
  attn<<<512, 256, 0, stream>>>(qb, kvb, lp, opp);
  combine<<<512, 256, 0, stream>>>(opp, lp, outp);
}